// Round 6
// baseline (32383.896 us; speedup 1.0000x reference)
//
#include <hip/hip_runtime.h>
#include <hip/hip_bf16.h>
#include <math.h>

#define BATCH 256
#define T_IN 256
#define T_OUT 32
#define E_DIM 512
#define H_DIM 1024
#define Y_DIM 1024
#define G_DIM 3072  // 3*H

typedef __attribute__((ext_vector_type(8))) __bf16 bf16x8;
typedef __attribute__((ext_vector_type(4))) float f32x4;
typedef __attribute__((ext_vector_type(4))) unsigned int u32x4;

__device__ __forceinline__ unsigned short f2bf_raw(float x) {
    unsigned int u = __builtin_bit_cast(unsigned int, x);
    u += 0x7FFFu + ((u >> 16) & 1u);
    return (unsigned short)(u >> 16);
}
__device__ __forceinline__ float bf2f(short s) {
    unsigned int u = ((unsigned int)(unsigned short)s) << 16;
    return __builtin_bit_cast(float, u);
}
__device__ __forceinline__ f32x4 mfma16(bf16x8 a, bf16x8 b, f32x4 c) {
    return __builtin_amdgcn_mfma_f32_16x16x32_bf16(a, b, c, 0, 0, 0);
}
__device__ __forceinline__ bf16x8 ldsb8(const short* p) {
    return __builtin_bit_cast(bf16x8, *(const u32x4*)p);
}
__device__ __forceinline__ bf16x8 zero_bf8() {
    u32x4 z = {0u, 0u, 0u, 0u};
    return __builtin_bit_cast(bf16x8, z);
}
__device__ __forceinline__ bf16x8 load_bf8(const short* p) {
    return __builtin_bit_cast(bf16x8, *(const u32x4*)p);
}
__device__ __forceinline__ bf16x8 load_f32_as_bf8(const float* p) {
    float4 f0 = *(const float4*)p;
    float4 f1 = *(const float4*)(p + 4);
    u32x4 v;
    v.x = ((unsigned)f2bf_raw(f0.y) << 16) | f2bf_raw(f0.x);
    v.y = ((unsigned)f2bf_raw(f0.w) << 16) | f2bf_raw(f0.z);
    v.z = ((unsigned)f2bf_raw(f1.y) << 16) | f2bf_raw(f1.x);
    v.w = ((unsigned)f2bf_raw(f1.w) << 16) | f2bf_raw(f1.z);
    return __builtin_bit_cast(bf16x8, v);
}

// ---------------------------------------------------------------------------
// f32 -> bf16 convert (weights, once per call)
// ---------------------------------------------------------------------------
__global__ __launch_bounds__(256) void f32_to_bf16(
    const float* __restrict__ src, short* __restrict__ dst, int n4)
{
    for (int i = blockIdx.x * 256 + threadIdx.x; i < n4; i += gridDim.x * 256) {
        float4 f = *(const float4*)(src + 4 * (size_t)i);
        short4 o;
        o.x = (short)f2bf_raw(f.x);
        o.y = (short)f2bf_raw(f.y);
        o.z = (short)f2bf_raw(f.z);
        o.w = (short)f2bf_raw(f.w);
        *(short4*)(dst + 4 * (size_t)i) = o;
    }
}

// ---------------------------------------------------------------------------
// Persistent 2-layer GRU recurrence. One launch runs `nsteps` diagonal steps:
// blocks 0..127 = layer0 (step t=k), blocks 128..255 = layer1 (step t=k-1).
// Grid barrier per step via monotone agent-scope atomic counter (grid=256
// blocks <= 256 CUs, 30KB LDS -> all blocks co-resident by capacity).
// Per block: 64 rows x 32 h-cols. W reg->LDS double buffer (row stride 34
// shorts = 17 words -> <=2-way bank alias, free). A operands global->reg.
// XCD swizzle: 4 m-tiles of one n-stripe land on one XCD (W L2-resident).
// ---------------------------------------------------------------------------
__global__ __launch_bounds__(256) void persist_kernel(
    int nsteps, int dec,
    const float* __restrict__ emb, const int* __restrict__ xind,
    const float* __restrict__ yv,
    const short* __restrict__ W0i, const short* __restrict__ W0h,
    const float* __restrict__ b0i, const float* __restrict__ b0h,
    const short* __restrict__ W1i, const short* __restrict__ W1h,
    const float* __restrict__ b1i, const float* __restrict__ b1h,
    float* __restrict__ h0f0v, float* __restrict__ h0f1v,
    short* __restrict__ h0b0v, short* __restrict__ h0b1v,
    float* __restrict__ h1f0v, float* __restrict__ h1f1v,
    short* __restrict__ h1b0v, short* __restrict__ h1b1v,
    short* __restrict__ copy_base,
    unsigned* __restrict__ bar)
{
    const int id = blockIdx.x;
    const int layer = id >> 7;
    const int cid = id & 127;
    const int nt = (cid & 7) * 4 + (cid >> 5);   // 0..31 h-col stripe
    const int mt = (cid >> 3) & 3;               // 0..3 row tile
    const int bm = mt * 64, bn = nt * 32;

    __shared__ __align__(16) short Ws[2][192 * 34];

    const int tid = threadIdx.x;
    const int lane = tid & 63;
    const int w = tid >> 6;
    const int wm = w & 1, wn = w >> 1;
    const int lr = lane & 15, lk = lane >> 4;

    const short* Wih = layer ? W1i : W0i;
    const short* Whh = layer ? W1h : W0h;
    const float* bih = layer ? b1i : b0i;
    const float* bhh = layer ? b1h : b0h;
    const int KW = layer ? H_DIM : (dec ? Y_DIM : E_DIM);  // Wih row stride

    // W staging descriptors (constant across steps): 3 x 16B per thread/K-step
    const short* wsrc[3]; int woff[3]; bool wih_f[3];
    #pragma unroll
    for (int j = 0; j < 3; ++j) {
        int lin = j * 256 + tid;          // 0..767
        int r = lin >> 2, c = lin & 3;    // r: 0..95 Wih, 96..191 Whh
        bool ih = (r < 96);
        int rr = ih ? r : r - 96;
        int g = rr >> 5;
        int col = bn + (rr & 31);
        wsrc[j] = (ih ? Wih : Whh) + (size_t)(g * H_DIM + col) * (ih ? KW : H_DIM) + c * 8;
        woff[j] = r * 34 + c * 8;
        wih_f[j] = ih;
    }

    const int r0 = bm + wm * 32 + lr;
    const int r1 = r0 + 16;
    const int colj = bn + wn * 16 + lr;
    const float bi0 = bih[colj], bi1 = bih[H_DIM + colj], bi2 = bih[2 * H_DIM + colj];
    const float bh0 = bhh[colj], bh1 = bhh[H_DIM + colj], bh2 = bhh[2 * H_DIM + colj];

    for (int k = 0; k < nsteps; ++k) {
        const bool active = layer ? (k >= 1) : (k < nsteps - 1);
        if (active) {
            // ---- per-step operand resolution ----
            int Kx;
            const float* axf0 = nullptr; const float* axf1 = nullptr;
            const short* axb0 = nullptr; const short* axb1 = nullptr;
            const short* hbf; const float* hf;
            float* houtf; short* houtbf; short* copyp = nullptr;
            if (layer == 0) {
                if (dec) {
                    if (k == 0) { Kx = 0; }
                    else {
                        Kx = Y_DIM;
                        axf0 = yv + ((size_t)r0 * T_OUT + (k - 1)) * Y_DIM + lk * 8;
                        axf1 = yv + ((size_t)r1 * T_OUT + (k - 1)) * Y_DIM + lk * 8;
                    }
                } else {
                    Kx = E_DIM;
                    int i0 = xind[(size_t)r0 * T_IN + k];
                    int i1 = xind[(size_t)r1 * T_IN + k];
                    axf0 = emb + (size_t)i0 * E_DIM + lk * 8;
                    axf1 = emb + (size_t)i1 * E_DIM + lk * 8;
                }
                hbf = (k & 1) ? h0b1v : h0b0v;
                hf  = (k & 1) ? h0f1v : h0f0v;
                houtf  = (k & 1) ? h0f0v : h0f1v;    // (k+1)&1
                houtbf = (k & 1) ? h0b0v : h0b1v;
            } else {
                Kx = H_DIM;
                const short* src = (k & 1) ? h0b1v : h0b0v;
                axb0 = src + (size_t)r0 * H_DIM + lk * 8;
                axb1 = src + (size_t)r1 * H_DIM + lk * 8;
                hbf = ((k - 1) & 1) ? h1b1v : h1b0v;
                hf  = ((k - 1) & 1) ? h1f1v : h1f0v;
                houtf  = (k & 1) ? h1f1v : h1f0v;
                houtbf = (k & 1) ? h1b1v : h1b0v;
                copyp = copy_base + (size_t)(k - 1) * BATCH * H_DIM;
            }
            const short* ah0p = hbf + (size_t)r0 * H_DIM + lk * 8;
            const short* ah1p = hbf + (size_t)r1 * H_DIM + lk * 8;

            int wlim[3];
            #pragma unroll
            for (int j = 0; j < 3; ++j) wlim[j] = wih_f[j] ? Kx : H_DIM;

            f32x4 zf = {0.f, 0.f, 0.f, 0.f};
            f32x4 accI[3][2] = {{zf, zf}, {zf, zf}, {zf, zf}};
            f32x4 accH[3][2] = {{zf, zf}, {zf, zf}, {zf, zf}};

            // ---- prologue: stage k0=0, load A(0) ----
            #pragma unroll
            for (int j = 0; j < 3; ++j)
                if (wlim[j] > 0) *(u32x4*)&Ws[0][woff[j]] = *(const u32x4*)(wsrc[j]);
            bf16x8 aH0 = load_bf8(ah0p), aH1 = load_bf8(ah1p);
            bf16x8 aX0 = zero_bf8(), aX1 = zero_bf8();
            if (Kx > 0) {
                if (axb0) { aX0 = load_bf8(axb0); aX1 = load_bf8(axb1); }
                else      { aX0 = load_f32_as_bf8(axf0); aX1 = load_f32_as_bf8(axf1); }
            }
            __syncthreads();

            int cur = 0;
            for (int k0 = 0; k0 < H_DIM; k0 += 32) {
                const int kn = k0 + 32;
                const bool more = kn < H_DIM;

                u32x4 wreg[3]; bool wact[3];
                #pragma unroll
                for (int j = 0; j < 3; ++j) {
                    wact[j] = more && (kn < wlim[j]);
                    if (wact[j]) wreg[j] = *(const u32x4*)(wsrc[j] + kn);
                }
                bf16x8 aH0n = zero_bf8(), aH1n = zero_bf8();
                bf16x8 aX0n = zero_bf8(), aX1n = zero_bf8();
                if (more) {
                    aH0n = load_bf8(ah0p + kn); aH1n = load_bf8(ah1p + kn);
                    if (kn < Kx) {
                        if (axb0) { aX0n = load_bf8(axb0 + kn); aX1n = load_bf8(axb1 + kn); }
                        else      { aX0n = load_f32_as_bf8(axf0 + kn); aX1n = load_f32_as_bf8(axf1 + kn); }
                    }
                }

                const short* wb = Ws[cur];
                #pragma unroll
                for (int g = 0; g < 3; ++g) {
                    bf16x8 wh = ldsb8(&wb[(96 + g * 32 + wn * 16 + lr) * 34 + lk * 8]);
                    accH[g][0] = mfma16(aH0, wh, accH[g][0]);
                    accH[g][1] = mfma16(aH1, wh, accH[g][1]);
                }
                if (k0 < Kx) {
                    #pragma unroll
                    for (int g = 0; g < 3; ++g) {
                        bf16x8 wi = ldsb8(&wb[(g * 32 + wn * 16 + lr) * 34 + lk * 8]);
                        accI[g][0] = mfma16(aX0, wi, accI[g][0]);
                        accI[g][1] = mfma16(aX1, wi, accI[g][1]);
                    }
                }

                short* wo = Ws[cur ^ 1];
                #pragma unroll
                for (int j = 0; j < 3; ++j)
                    if (wact[j]) *(u32x4*)&wo[woff[j]] = wreg[j];
                __syncthreads();

                aH0 = aH0n; aH1 = aH1n; aX0 = aX0n; aX1 = aX1n;
                cur ^= 1;
            }

            // ---- GRU epilogue (torch gate order r,z,n) ----
            #pragma unroll
            for (int mf = 0; mf < 2; ++mf) {
                #pragma unroll
                for (int q = 0; q < 4; ++q) {
                    int row = bm + wm * 32 + mf * 16 + lk * 4 + q;
                    float ir = accI[0][mf][q] + bi0, hr = accH[0][mf][q] + bh0;
                    float iz = accI[1][mf][q] + bi1, hz = accH[1][mf][q] + bh1;
                    float in_ = accI[2][mf][q] + bi2, hn = accH[2][mf][q] + bh2;
                    float r = 1.f / (1.f + expf(-(ir + hr)));
                    float z = 1.f / (1.f + expf(-(iz + hz)));
                    float n = tanhf(in_ + r * hn);
                    size_t oi = (size_t)row * H_DIM + colj;
                    float hv = hf[oi];
                    float o = (1.f - z) * n + z * hv;
                    houtf[oi] = o;
                    short ob = (short)f2bf_raw(o);
                    houtbf[oi] = ob;
                    if (copyp) copyp[oi] = ob;
                }
            }
        }

        // ---- grid barrier (monotone counter; agent scope for cross-XCD) ----
        __syncthreads();
        if (tid == 0) {
            __threadfence();  // agent release: make h writes visible
            __hip_atomic_fetch_add(bar, 1u, __ATOMIC_RELEASE, __HIP_MEMORY_SCOPE_AGENT);
            const unsigned tgt = (unsigned)(k + 1) * 256u;
            while (__hip_atomic_load(bar, __ATOMIC_ACQUIRE, __HIP_MEMORY_SCOPE_AGENT) < tgt)
                __builtin_amdgcn_s_sleep(2);
            __threadfence();  // agent acquire: invalidate stale L1/L2 lines
        }
        __syncthreads();
    }
}

// ---------------------------------------------------------------------------
// scores: S[b][t][s] = dot(h2all[t][b][:], enc[s][b][:]) — MFMA, all t at once
// ---------------------------------------------------------------------------
__global__ __launch_bounds__(256) void score_gemm(
    const short* __restrict__ h2all, const short* __restrict__ enc,
    float* __restrict__ S)
{
    const int st = blockIdx.x;
    const int b = blockIdx.y;
    __shared__ __align__(16) short Hs[32 * 40];
    __shared__ __align__(16) short Es[64 * 40];
    const int tid = threadIdx.x;
    const int ch = (tid & 3) * 8;
    const int hrow = (tid >> 2) & 31;
    const int erow = tid >> 2;
    const short* hsrc = h2all + ((size_t)hrow * BATCH + b) * H_DIM + ch;
    const short* esrc = enc + ((size_t)(st * 64 + erow) * BATCH + b) * H_DIM + ch;
    short* hdst = &Hs[hrow * 40 + ch];
    short* edst = &Es[erow * 40 + ch];

    const int lane = tid & 63, w = tid >> 6;
    const int lr = lane & 15, ko = (lane >> 4) * 8;
    f32x4 acc0 = {0.f, 0.f, 0.f, 0.f}, acc1 = acc0;
    for (int k0 = 0; k0 < H_DIM; k0 += 32) {
        if (tid < 128) *(u32x4*)hdst = *(const u32x4*)(hsrc + k0);
        *(u32x4*)edst = *(const u32x4*)(esrc + k0);
        __syncthreads();
        bf16x8 e = ldsb8(&Es[(w * 16 + lr) * 40 + ko]);
        bf16x8 h0v = ldsb8(&Hs[lr * 40 + ko]);
        bf16x8 h1v = ldsb8(&Hs[(16 + lr) * 40 + ko]);
        acc0 = mfma16(h0v, e, acc0);
        acc1 = mfma16(h1v, e, acc1);
        __syncthreads();
    }
    int s = st * 64 + w * 16 + lr;
    #pragma unroll
    for (int q = 0; q < 4; ++q) {
        int t0 = (lane >> 4) * 4 + q;
        S[(size_t)b * 8192 + (size_t)t0 * 256 + s] = acc0[q];
        S[(size_t)b * 8192 + (size_t)(t0 + 16) * 256 + s] = acc1[q];
    }
}

// softmax over s (256) per (b,t) row; grid 8192
__global__ __launch_bounds__(256) void softmax_all(float* __restrict__ S)
{
    size_t base = (size_t)blockIdx.x * 256;
    int t = threadIdx.x;
    float v = S[base + t];
    int lane = t & 63, w = t >> 6;
    float m = v;
    for (int off = 32; off; off >>= 1) m = fmaxf(m, __shfl_down(m, off));
    __shared__ float r1[4];
    if (!lane) r1[w] = m;
    __syncthreads();
    m = fmaxf(fmaxf(r1[0], r1[1]), fmaxf(r1[2], r1[3]));
    float ex = expf(v - m);
    float s = ex;
    for (int off = 32; off; off >>= 1) s += __shfl_down(s, off);
    __shared__ float r2[4];
    if (!lane) r2[w] = s;
    __syncthreads();
    s = r2[0] + r2[1] + r2[2] + r2[3];
    S[base + t] = ex / s;
}

// attn_bf[m=t*256+b][h] = sum_s alpha[b][t][s] * enc[s][b][h]; grid (4 tc, 256 b)
__global__ __launch_bounds__(256) void attn_apply_all(
    const short* __restrict__ enc, const float* __restrict__ S,
    short* __restrict__ attn_bf)
{
    const int tc = blockIdx.x, b = blockIdx.y;
    __shared__ float al[8][256];
    const int tid = threadIdx.x;
    #pragma unroll
    for (int ti = 0; ti < 8; ++ti)
        al[ti][tid] = S[(size_t)b * 8192 + (size_t)(tc * 8 + ti) * 256 + tid];
    __syncthreads();
    float acc[8][4] = {};
    const short* eb = enc + (size_t)b * H_DIM + tid;
    for (int s = 0; s < 256; ++s) {
        const short* er = eb + (size_t)s * (BATCH * H_DIM);
        float e0 = bf2f(er[0]), e1 = bf2f(er[256]);
        float e2 = bf2f(er[512]), e3 = bf2f(er[768]);
        #pragma unroll
        for (int ti = 0; ti < 8; ++ti) {
            float av = al[ti][s];
            acc[ti][0] += av * e0; acc[ti][1] += av * e1;
            acc[ti][2] += av * e2; acc[ti][3] += av * e3;
        }
    }
    #pragma unroll
    for (int ti = 0; ti < 8; ++ti) {
        size_t m = (size_t)(tc * 8 + ti) * 256 + b;
        #pragma unroll
        for (int i = 0; i < 4; ++i)
            attn_bf[m * H_DIM + tid + i * 256] = (short)f2bf_raw(acc[ti][i]);
    }
}

// ---------------------------------------------------------------------------
// logits[m][n] = attn[m]@mapW[n][:1024] + h2[m]@mapW[n][1024:] + b[n]
// ---------------------------------------------------------------------------
__global__ __launch_bounds__(256) void map_gemm(
    const short* __restrict__ A1, const short* __restrict__ A2,
    const short* __restrict__ Wm, const float* __restrict__ bias,
    float* __restrict__ C)
{
    const int bm = blockIdx.x * 64, bn = blockIdx.y * 64;
    __shared__ __align__(16) short S1[64 * 40], S2[64 * 40], T1[64 * 40], T2[64 * 40];
    const int tid = threadIdx.x;
    const int r = tid >> 2, ch = (tid & 3) * 8;
    const short* a1 = A1 + (size_t)(bm + r) * 1024 + ch;
    const short* a2 = A2 + (size_t)(bm + r) * 1024 + ch;
    const short* w1 = Wm + (size_t)(bn + r) * 2048 + ch;
    const short* w2 = w1 + 1024;
    const int lane = tid & 63, w = tid >> 6;
    const int wm = (w >> 1) * 32, wn = (w & 1) * 32;
    const int lr = lane & 15, ko = (lane >> 4) * 8;
    f32x4 acc[2][2] = {{{0.f,0.f,0.f,0.f}}};
    for (int k0 = 0; k0 < 1024; k0 += 32) {
        *(u32x4*)&S1[r * 40 + ch] = *(const u32x4*)(a1 + k0);
        *(u32x4*)&S2[r * 40 + ch] = *(const u32x4*)(a2 + k0);
        *(u32x4*)&T1[r * 40 + ch] = *(const u32x4*)(w1 + k0);
        *(u32x4*)&T2[r * 40 + ch] = *(const u32x4*)(w2 + k0);
        __syncthreads();
        bf16x8 x1[2], x2[2], y1[2], y2[2];
        #pragma unroll
        for (int i = 0; i < 2; ++i) {
            x1[i] = ldsb8(&S1[(wm + i * 16 + lr) * 40 + ko]);
            x2[i] = ldsb8(&S2[(wm + i * 16 + lr) * 40 + ko]);
            y1[i] = ldsb8(&T1[(wn + i * 16 + lr) * 40 + ko]);
            y2[i] = ldsb8(&T2[(wn + i * 16 + lr) * 40 + ko]);
        }
        #pragma unroll
        for (int i = 0; i < 2; ++i) {
            #pragma unroll
            for (int jq = 0; jq < 2; ++jq) {
                acc[i][jq] = mfma16(x1[i], y1[jq], acc[i][jq]);
                acc[i][jq] = mfma16(x2[i], y2[jq], acc[i][jq]);
            }
        }
        __syncthreads();
    }
    #pragma unroll
    for (int i = 0; i < 2; ++i) {
        #pragma unroll
        for (int jq = 0; jq < 2; ++jq) {
            int col = bn + wn + jq * 16 + lr;
            float bv = bias[col];
            #pragma unroll
            for (int q = 0; q < 4; ++q) {
                int row = bm + wm + i * 16 + (lane >> 4) * 4 + q;
                C[(size_t)row * 1024 + col] = acc[i][jq][q] + bv;
            }
        }
    }
}

// loss over all (t,b) rows; grid 8192, m = t*256+b
__global__ __launch_bounds__(256) void loss_all(
    const float* __restrict__ logits, const float* __restrict__ y,
    float* __restrict__ loss_acc)
{
    int m = blockIdx.x, t = threadIdx.x;
    int tt = m >> 8, b = m & 255;
    const float* lrow = logits + (size_t)m * Y_DIM;
    float l[4];
    #pragma unroll
    for (int i = 0; i < 4; ++i) l[i] = lrow[t + i * 256];
    float mx = fmaxf(fmaxf(l[0], l[1]), fmaxf(l[2], l[3]));
    int lane = t & 63, w = t >> 6;
    for (int off = 32; off; off >>= 1) mx = fmaxf(mx, __shfl_down(mx, off));
    __shared__ float sm[4];
    if (!lane) sm[w] = mx;
    __syncthreads();
    mx = fmaxf(fmaxf(sm[0], sm[1]), fmaxf(sm[2], sm[3]));
    float es = 0.f;
    #pragma unroll
    for (int i = 0; i < 4; ++i) es += expf(l[i] - mx);
    for (int off = 32; off; off >>= 1) es += __shfl_down(es, off);
    __shared__ float ss[4];
    if (!lane) ss[w] = es;
    __syncthreads();
    float sum = ss[0] + ss[1] + ss[2] + ss[3];
    float logZ = mx + logf(sum);
    const float* yrow = y + ((size_t)b * T_OUT + tt) * Y_DIM;
    float part = 0.f;
    #pragma unroll
    for (int i = 0; i < 4; ++i) part += yrow[t + i * 256] * (logZ - l[i]);
    for (int off = 32; off; off >>= 1) part += __shfl_down(part, off);
    __shared__ float sp[4];
    if (!lane) sp[w] = part;
    __syncthreads();
    if (t == 0) atomicAdd(loss_acc, sp[0] + sp[1] + sp[2] + sp[3]);
}

__global__ __launch_bounds__(256) void ysum_kernel(
    const float* __restrict__ y, float* __restrict__ ysum, int n)
{
    float s = 0.f;
    for (int i = blockIdx.x * 256 + threadIdx.x; i < n; i += gridDim.x * 256)
        s += y[i];
    int lane = threadIdx.x & 63, w = threadIdx.x >> 6;
    for (int off = 32; off; off >>= 1) s += __shfl_down(s, off);
    __shared__ float sw[4];
    if (!lane) sw[w] = s;
    __syncthreads();
    if (!threadIdx.x) atomicAdd(ysum, sw[0] + sw[1] + sw[2] + sw[3]);
}

__global__ __launch_bounds__(256) void init_kernel(
    float* __restrict__ h0, float* __restrict__ h1,
    short* __restrict__ h0b, short* __restrict__ h1b,
    float* __restrict__ loss, float* __restrict__ ysum,
    unsigned* __restrict__ bar)
{
    int i = blockIdx.x * 256 + threadIdx.x;   // 0..B*H-1
    h0[i] = 0.f; h1[i] = 0.f; h0b[i] = 0; h1b[i] = 0;
    if (i == 0) { *loss = 0.f; *ysum = 0.f; bar[0] = 0u; bar[1] = 0u; }
}

__global__ void final_kernel(const float* __restrict__ loss,
                             const float* __restrict__ ysum,
                             float* __restrict__ out)
{
    if (threadIdx.x == 0) out[0] = loss[0] / ysum[0];
}

// ---------------------------------------------------------------------------
extern "C" void kernel_launch(void* const* d_in, const int* in_sizes, int n_in,
                              void* d_out, int out_size, void* d_ws, size_t ws_size,
                              hipStream_t stream)
{
    const int*   x     = (const int*)d_in[0];
    const float* y     = (const float*)d_in[1];
    const float* emb   = (const float*)d_in[2];
    const float* eWih0 = (const float*)d_in[3];
    const float* eWhh0 = (const float*)d_in[4];
    const float* ebih0 = (const float*)d_in[5];
    const float* ebhh0 = (const float*)d_in[6];
    const float* eWih1 = (const float*)d_in[7];
    const float* eWhh1 = (const float*)d_in[8];
    const float* ebih1 = (const float*)d_in[9];
    const float* ebhh1 = (const float*)d_in[10];
    const float* dWih0 = (const float*)d_in[11];
    const float* dWhh0 = (const float*)d_in[12];
    const float* dbih0 = (const float*)d_in[13];
    const float* dbhh0 = (const float*)d_in[14];
    const float* dWih1 = (const float*)d_in[15];
    const float* dWhh1 = (const float*)d_in[16];
    const float* dbih1 = (const float*)d_in[17];
    const float* dbhh1 = (const float*)d_in[18];
    const float* mapW  = (const float*)d_in[19];
    const float* mapb  = (const float*)d_in[20];
    float* out = (float*)d_out;

    // ---- workspace layout (~200 MB live peak; aliases reuse dead regions) ----
    char* p = (char*)d_ws;
    auto take = [&](size_t n) { char* q = p; p += (n + 255) & ~(size_t)255; return q; };
    short* enc_bf = (short*)take((size_t)T_IN * BATCH * H_DIM * 2);   // 134 MB
    char* wslab = p;
    short* eWih0b = (short*)take((size_t)G_DIM * E_DIM * 2);
    short* eWhh0b = (short*)take((size_t)G_DIM * H_DIM * 2);
    short* eWih1b = (short*)take((size_t)G_DIM * H_DIM * 2);
    short* eWhh1b = (short*)take((size_t)G_DIM * H_DIM * 2);
    short* dWih0b = (short*)take((size_t)G_DIM * Y_DIM * 2);
    short* dWhh0b = (short*)take((size_t)G_DIM * H_DIM * 2);
    short* dWih1b = (short*)take((size_t)G_DIM * H_DIM * 2);
    short* dWhh1b = (short*)take((size_t)G_DIM * H_DIM * 2);
    short* mapWb  = (short*)take((size_t)Y_DIM * 2 * H_DIM * 2);
    float* h0f[2]; float* h1f[2]; short* h0b[2]; short* h1b[2];
    for (int i = 0; i < 2; ++i) {
        h0f[i] = (float*)take((size_t)BATCH * H_DIM * 4);
        h1f[i] = (float*)take((size_t)BATCH * H_DIM * 4);
        h0b[i] = (short*)take((size_t)BATCH * H_DIM * 2);
        h1b[i] = (short*)take((size_t)BATCH * H_DIM * 2);
    }
    short* h2all = (short*)take((size_t)T_OUT * BATCH * H_DIM * 2);   // 16.8 MB
    float* loss_acc = (float*)take(256);
    float* ysum = loss_acc + 1;
    unsigned* bar = (unsigned*)(loss_acc + 8);   // bar[0]=enc, bar[1]=dec
    // aliases onto dead regions:
    float* logits  = (float*)enc_bf;                       // enc dead at map time
    short* attn_bf = (short*)wslab;                        // over dead enc weights
    float* S       = (float*)(wslab + (size_t)20 * 1024 * 1024);

    dim3 blk(256);

    // ---- weight conversion ----
    f32_to_bf16<<<dim3(512), blk, 0, stream>>>(eWih0, eWih0b, G_DIM * E_DIM / 4);
    f32_to_bf16<<<dim3(512), blk, 0, stream>>>(eWhh0, eWhh0b, G_DIM * H_DIM / 4);
    f32_to_bf16<<<dim3(512), blk, 0, stream>>>(eWih1, eWih1b, G_DIM * H_DIM / 4);
    f32_to_bf16<<<dim3(512), blk, 0, stream>>>(eWhh1, eWhh1b, G_DIM * H_DIM / 4);
    f32_to_bf16<<<dim3(512), blk, 0, stream>>>(dWih0, dWih0b, G_DIM * Y_DIM / 4);
    f32_to_bf16<<<dim3(512), blk, 0, stream>>>(dWhh0, dWhh0b, G_DIM * H_DIM / 4);
    f32_to_bf16<<<dim3(512), blk, 0, stream>>>(dWih1, dWih1b, G_DIM * H_DIM / 4);
    f32_to_bf16<<<dim3(512), blk, 0, stream>>>(dWhh1, dWhh1b, G_DIM * H_DIM / 4);
    f32_to_bf16<<<dim3(512), blk, 0, stream>>>(mapW, mapWb, Y_DIM * 2 * H_DIM / 4);

    init_kernel<<<dim3(BATCH * H_DIM / 256), blk, 0, stream>>>(
        h0f[0], h1f[0], h0b[0], h1b[0], loss_acc, ysum, bar);
    ysum_kernel<<<dim3(2048), blk, 0, stream>>>(y, ysum, BATCH * T_OUT * Y_DIM);

    // -------- encoder: one persistent launch, 257 diagonal steps --------
    persist_kernel<<<dim3(256), blk, 0, stream>>>(
        T_IN + 1, 0, emb, x, y,
        eWih0b, eWhh0b, ebih0, ebhh0,
        eWih1b, eWhh1b, ebih1, ebhh1,
        h0f[0], h0f[1], h0b[0], h0b[1],
        h1f[0], h1f[1], h1b[0], h1b[1],
        enc_bf, bar);

    // -------- decoder GRU chain: one persistent launch, 33 steps --------
    persist_kernel<<<dim3(256), blk, 0, stream>>>(
        T_OUT + 1, 1, emb, x, y,
        dWih0b, dWhh0b, dbih0, dbhh0,
        dWih1b, dWhh1b, dbih1, dbhh1,
        h0f[0], h0f[1], h0b[0], h0b[1],
        h1f[0], h1f[1], h1b[0], h1b[1],
        h2all, bar + 1);

    // -------- batched attention + map + loss over all 32 decoder steps ----
    score_gemm<<<dim3(4, 256), blk, 0, stream>>>(h2all, enc_bf, S);
    softmax_all<<<dim3(8192), blk, 0, stream>>>(S);
    attn_apply_all<<<dim3(4, 256), blk, 0, stream>>>(enc_bf, S, attn_bf);
    map_gemm<<<dim3(128, 16), blk, 0, stream>>>(attn_bf, h2all, mapWb, mapb, logits);
    loss_all<<<dim3(8192), blk, 0, stream>>>(logits, y, loss_acc);

    final_kernel<<<dim3(1), dim3(64), 0, stream>>>(loss_acc, ysum, out);
}

// Round 7
// 22441.893 us; speedup vs baseline: 1.4430x; 1.4430x over previous
//
#include <hip/hip_runtime.h>
#include <hip/hip_bf16.h>
#include <math.h>

#define BATCH 256
#define T_IN 256
#define T_OUT 32
#define E_DIM 512
#define H_DIM 1024
#define Y_DIM 1024
#define G_DIM 3072  // 3*H
#define RS 34       // LDS row stride in shorts (17 words, odd -> <=2-way bank alias)

typedef __attribute__((ext_vector_type(8))) __bf16 bf16x8;
typedef __attribute__((ext_vector_type(4))) float f32x4;
typedef __attribute__((ext_vector_type(4))) unsigned int u32x4;

__device__ __forceinline__ unsigned short f2bf_raw(float x) {
    unsigned int u = __builtin_bit_cast(unsigned int, x);
    u += 0x7FFFu + ((u >> 16) & 1u);
    return (unsigned short)(u >> 16);
}
__device__ __forceinline__ float bf2f(short s) {
    unsigned int u = ((unsigned int)(unsigned short)s) << 16;
    return __builtin_bit_cast(float, u);
}
__device__ __forceinline__ f32x4 mfma16(bf16x8 a, bf16x8 b, f32x4 c) {
    return __builtin_amdgcn_mfma_f32_16x16x32_bf16(a, b, c, 0, 0, 0);
}
__device__ __forceinline__ bf16x8 ldsb8(const short* p) {
    return __builtin_bit_cast(bf16x8, *(const u32x4*)p);
}
__device__ __forceinline__ u32x4 conv_f32x8(const float* p) {
    float4 f0 = *(const float4*)p;
    float4 f1 = *(const float4*)(p + 4);
    u32x4 v;
    v.x = ((unsigned)f2bf_raw(f0.y) << 16) | f2bf_raw(f0.x);
    v.y = ((unsigned)f2bf_raw(f0.w) << 16) | f2bf_raw(f0.z);
    v.z = ((unsigned)f2bf_raw(f1.y) << 16) | f2bf_raw(f1.x);
    v.w = ((unsigned)f2bf_raw(f1.w) << 16) | f2bf_raw(f1.z);
    return v;
}

// ---------------------------------------------------------------------------
// f32 -> bf16 convert (weights, once per call)
// ---------------------------------------------------------------------------
__global__ __launch_bounds__(256) void f32_to_bf16(
    const float* __restrict__ src, short* __restrict__ dst, int n4)
{
    for (int i = blockIdx.x * 256 + threadIdx.x; i < n4; i += gridDim.x * 256) {
        float4 f = *(const float4*)(src + 4 * (size_t)i);
        short4 o;
        o.x = (short)f2bf_raw(f.x);
        o.y = (short)f2bf_raw(f.y);
        o.z = (short)f2bf_raw(f.z);
        o.w = (short)f2bf_raw(f.w);
        *(short4*)(dst + 4 * (size_t)i) = o;
    }
}

// ---------------------------------------------------------------------------
// Fused GRU cell v3. Two independent cells per launch (blockIdx >= 256 -> B).
// 512 blocks of 32 rows x 32 h-cols => 2 blocks/CU (8 waves/CU).
// LDS row stride 34 shorts -> <=2-way bank alias (R6-validated numerics).
// Single-buffer two-sync staging (R4-style; prefetch variant regressed).
// XCD swizzle: blocks sharing a W col-stripe are congruent mod 8 -> W slice
// (~2.8MB/XCD, both cells) stays L2-resident across steps.
// ---------------------------------------------------------------------------
struct CellArgs {
    const float* Af; const short* Ab; const int* gat; int gs; int lda; int Kx;
    const short* Wih; const short* Whh;
    const float* bih; const float* bhh;
    const short* hbf;   // bf16 h_prev (GEMM operand)
    const float* hf;    // f32  h_prev (GRU combine)
    float* houtf; short* houtbf; short* copy;
    int active;
};

__global__ __launch_bounds__(256, 2) void cell3(CellArgs cA, CellArgs cB)
{
    const int id = blockIdx.x;
    const CellArgs a = (id >= 256) ? cB : cA;
    if (!a.active) return;
    const int cid = id & 255;
    const int nt = (cid & 7) * 4 + ((cid >> 3) & 3);   // 0..31 h-col stripe
    const int mt = cid >> 5;                           // 0..7 row tile
    const int bm = mt * 32, bn = nt * 32;

    __shared__ __align__(16) short As[2 * 32 * RS];   // [src][32 rows][RS]
    __shared__ __align__(16) short Ws[192 * RS];      // [2mat*3g*32col][RS]

    const int tid = threadIdx.x;
    const int lane = tid & 63;
    const int w = tid >> 6;
    const int wm = w & 1, wn = w >> 1;
    const int lr = lane & 15, lk = lane >> 4;
    const int Kx = a.Kx;

    // ---- A staging: 1 x 16B chunk per thread per K-step ----
    const int ss = tid >> 7;          // 0 = x-src, 1 = h-src
    const int sr = (tid >> 2) & 31;   // tile row
    const int ch = (tid & 3) * 8;     // chunk offset (shorts)
    const float* axf = nullptr; const short* axb = nullptr;
    if (ss == 0 && Kx > 0) {
        if (a.Ab) {
            axb = a.Ab + (size_t)(bm + sr) * a.lda + ch;
        } else {
            int ridx = a.gat ? a.gat[(size_t)(bm + sr) * a.gs] : (bm + sr);
            axf = a.Af + (size_t)ridx * a.lda + ch;
        }
    }
    const short* ahs = a.hbf + (size_t)(bm + sr) * H_DIM + ch;
    short* adst = &As[ss * (32 * RS) + sr * RS + ch];

    // ---- W staging: 3 x 16B chunks per thread per K-step ----
    const short* wsrc[3]; int woff[3]; int wlim[3];
    #pragma unroll
    for (int j = 0; j < 3; ++j) {
        int lin = j * 256 + tid;          // 0..767
        int r = lin >> 2, c = lin & 3;    // r: 0..95 Wih, 96..191 Whh
        bool ih = (r < 96);
        int rr = ih ? r : r - 96;
        int g = rr >> 5;
        int col = bn + (rr & 31);
        int K = ih ? Kx : H_DIM;
        wsrc[j] = (ih ? a.Wih : a.Whh) + (size_t)(g * H_DIM + col) * K + c * 8;
        woff[j] = r * RS + c * 8;
        wlim[j] = K;
    }

    // compute-side LDS pointers
    const short* pax = &As[(wm * 16 + lr) * RS + lk * 8];
    const short* pah = &As[32 * RS + (wm * 16 + lr) * RS + lk * 8];

    f32x4 zf = {0.f, 0.f, 0.f, 0.f};
    f32x4 accI[3] = {zf, zf, zf};
    f32x4 accH[3] = {zf, zf, zf};

    for (int k0 = 0; k0 < H_DIM; k0 += 32) {
        // ---- stage ----
        if (ss == 0) {
            if (k0 < Kx) {
                u32x4 av;
                if (axb) av = *(const u32x4*)(axb + k0);
                else     av = conv_f32x8(axf + k0);
                *(u32x4*)adst = av;
            }
        } else {
            *(u32x4*)adst = *(const u32x4*)(ahs + k0);
        }
        #pragma unroll
        for (int j = 0; j < 3; ++j)
            if (k0 < wlim[j]) *(u32x4*)&Ws[woff[j]] = *(const u32x4*)(wsrc[j] + k0);
        __syncthreads();

        // ---- compute ----
        bf16x8 aH = ldsb8(pah);
        #pragma unroll
        for (int g = 0; g < 3; ++g) {
            bf16x8 wh = ldsb8(&Ws[(96 + g * 32 + wn * 16 + lr) * RS + lk * 8]);
            accH[g] = mfma16(aH, wh, accH[g]);
        }
        if (k0 < Kx) {
            bf16x8 aX = ldsb8(pax);
            #pragma unroll
            for (int g = 0; g < 3; ++g) {
                bf16x8 wi = ldsb8(&Ws[(g * 32 + wn * 16 + lr) * RS + lk * 8]);
                accI[g] = mfma16(aX, wi, accI[g]);
            }
        }
        __syncthreads();
    }

    // ---- GRU epilogue (torch gate order r,z,n) ----
    const int colj = bn + wn * 16 + lr;
    const float bi0 = a.bih[colj], bi1 = a.bih[H_DIM + colj], bi2 = a.bih[2 * H_DIM + colj];
    const float bh0 = a.bhh[colj], bh1 = a.bhh[H_DIM + colj], bh2 = a.bhh[2 * H_DIM + colj];
    #pragma unroll
    for (int q = 0; q < 4; ++q) {
        int row = bm + wm * 16 + lk * 4 + q;
        float ir = accI[0][q] + bi0, hr = accH[0][q] + bh0;
        float iz = accI[1][q] + bi1, hz = accH[1][q] + bh1;
        float in_ = accI[2][q] + bi2, hn = accH[2][q] + bh2;
        float r = 1.f / (1.f + expf(-(ir + hr)));
        float z = 1.f / (1.f + expf(-(iz + hz)));
        float n = tanhf(in_ + r * hn);
        size_t oi = (size_t)row * H_DIM + colj;
        float hv = a.hf[oi];
        float o = (1.f - z) * n + z * hv;
        a.houtf[oi] = o;
        short ob = (short)f2bf_raw(o);
        a.houtbf[oi] = ob;
        if (a.copy) a.copy[oi] = ob;
    }
}

// ---------------------------------------------------------------------------
// scores: S[b][t][s] = dot(h2all[t][b][:], enc[s][b][:]) — MFMA, all t at once
// ---------------------------------------------------------------------------
__global__ __launch_bounds__(256) void score_gemm(
    const short* __restrict__ h2all, const short* __restrict__ enc,
    float* __restrict__ S)
{
    const int st = blockIdx.x;
    const int b = blockIdx.y;
    __shared__ __align__(16) short Hs[32 * 40];
    __shared__ __align__(16) short Es[64 * 40];
    const int tid = threadIdx.x;
    const int ch = (tid & 3) * 8;
    const int hrow = (tid >> 2) & 31;
    const int erow = tid >> 2;
    const short* hsrc = h2all + ((size_t)hrow * BATCH + b) * H_DIM + ch;
    const short* esrc = enc + ((size_t)(st * 64 + erow) * BATCH + b) * H_DIM + ch;
    short* hdst = &Hs[hrow * 40 + ch];
    short* edst = &Es[erow * 40 + ch];

    const int lane = tid & 63, w = tid >> 6;
    const int lr = lane & 15, ko = (lane >> 4) * 8;
    f32x4 acc0 = {0.f, 0.f, 0.f, 0.f}, acc1 = acc0;
    for (int k0 = 0; k0 < H_DIM; k0 += 32) {
        if (tid < 128) *(u32x4*)hdst = *(const u32x4*)(hsrc + k0);
        *(u32x4*)edst = *(const u32x4*)(esrc + k0);
        __syncthreads();
        bf16x8 e = ldsb8(&Es[(w * 16 + lr) * 40 + ko]);
        bf16x8 h0v = ldsb8(&Hs[lr * 40 + ko]);
        bf16x8 h1v = ldsb8(&Hs[(16 + lr) * 40 + ko]);
        acc0 = mfma16(h0v, e, acc0);
        acc1 = mfma16(h1v, e, acc1);
        __syncthreads();
    }
    int s = st * 64 + w * 16 + lr;
    #pragma unroll
    for (int q = 0; q < 4; ++q) {
        int t0 = (lane >> 4) * 4 + q;
        S[(size_t)b * 8192 + (size_t)t0 * 256 + s] = acc0[q];
        S[(size_t)b * 8192 + (size_t)(t0 + 16) * 256 + s] = acc1[q];
    }
}

// softmax over s (256) per (b,t) row; grid 8192
__global__ __launch_bounds__(256) void softmax_all(float* __restrict__ S)
{
    size_t base = (size_t)blockIdx.x * 256;
    int t = threadIdx.x;
    float v = S[base + t];
    int lane = t & 63, w = t >> 6;
    float m = v;
    for (int off = 32; off; off >>= 1) m = fmaxf(m, __shfl_down(m, off));
    __shared__ float r1[4];
    if (!lane) r1[w] = m;
    __syncthreads();
    m = fmaxf(fmaxf(r1[0], r1[1]), fmaxf(r1[2], r1[3]));
    float ex = expf(v - m);
    float s = ex;
    for (int off = 32; off; off >>= 1) s += __shfl_down(s, off);
    __shared__ float r2[4];
    if (!lane) r2[w] = s;
    __syncthreads();
    s = r2[0] + r2[1] + r2[2] + r2[3];
    S[base + t] = ex / s;
}

// attn_bf[m=t*256+b][h] = sum_s alpha[b][t][s] * enc[s][b][h]; grid (4 tc, 256 b)
__global__ __launch_bounds__(256) void attn_apply_all(
    const short* __restrict__ enc, const float* __restrict__ S,
    short* __restrict__ attn_bf)
{
    const int tc = blockIdx.x, b = blockIdx.y;
    __shared__ float al[8][256];
    const int tid = threadIdx.x;
    #pragma unroll
    for (int ti = 0; ti < 8; ++ti)
        al[ti][tid] = S[(size_t)b * 8192 + (size_t)(tc * 8 + ti) * 256 + tid];
    __syncthreads();
    float acc[8][4] = {};
    const short* eb = enc + (size_t)b * H_DIM + tid;
    for (int s = 0; s < 256; ++s) {
        const short* er = eb + (size_t)s * (BATCH * H_DIM);
        float e0 = bf2f(er[0]), e1 = bf2f(er[256]);
        float e2 = bf2f(er[512]), e3 = bf2f(er[768]);
        #pragma unroll
        for (int ti = 0; ti < 8; ++ti) {
            float av = al[ti][s];
            acc[ti][0] += av * e0; acc[ti][1] += av * e1;
            acc[ti][2] += av * e2; acc[ti][3] += av * e3;
        }
    }
    #pragma unroll
    for (int ti = 0; ti < 8; ++ti) {
        size_t m = (size_t)(tc * 8 + ti) * 256 + b;
        #pragma unroll
        for (int i = 0; i < 4; ++i)
            attn_bf[m * H_DIM + tid + i * 256] = (short)f2bf_raw(acc[ti][i]);
    }
}

// ---------------------------------------------------------------------------
// logits[m][n] = attn[m]@mapW[n][:1024] + h2[m]@mapW[n][1024:] + b[n]
// ---------------------------------------------------------------------------
__global__ __launch_bounds__(256) void map_gemm(
    const short* __restrict__ A1, const short* __restrict__ A2,
    const short* __restrict__ Wm, const float* __restrict__ bias,
    float* __restrict__ C)
{
    const int bm = blockIdx.x * 64, bn = blockIdx.y * 64;
    __shared__ __align__(16) short S1[64 * 40], S2[64 * 40], T1[64 * 40], T2[64 * 40];
    const int tid = threadIdx.x;
    const int r = tid >> 2, ch = (tid & 3) * 8;
    const short* a1 = A1 + (size_t)(bm + r) * 1024 + ch;
    const short* a2 = A2 + (size_t)(bm + r) * 1024 + ch;
    const short* w1 = Wm + (size_t)(bn + r) * 2048 + ch;
    const short* w2 = w1 + 1024;
    const int lane = tid & 63, w = tid >> 6;
    const int wm = (w >> 1) * 32, wn = (w & 1) * 32;
    const int lr = lane & 15, ko = (lane >> 4) * 8;
    f32x4 acc[2][2] = {{{0.f,0.f,0.f,0.f}}};
    for (int k0 = 0; k0 < 1024; k0 += 32) {
        *(u32x4*)&S1[r * 40 + ch] = *(const u32x4*)(a1 + k0);
        *(u32x4*)&S2[r * 40 + ch] = *(const u32x4*)(a2 + k0);
        *(u32x4*)&T1[r * 40 + ch] = *(const u32x4*)(w1 + k0);
        *(u32x4*)&T2[r * 40 + ch] = *(const u32x4*)(w2 + k0);
        __syncthreads();
        bf16x8 x1[2], x2[2], y1[2], y2[2];
        #pragma unroll
        for (int i = 0; i < 2; ++i) {
            x1[i] = ldsb8(&S1[(wm + i * 16 + lr) * 40 + ko]);
            x2[i] = ldsb8(&S2[(wm + i * 16 + lr) * 40 + ko]);
            y1[i] = ldsb8(&T1[(wn + i * 16 + lr) * 40 + ko]);
            y2[i] = ldsb8(&T2[(wn + i * 16 + lr) * 40 + ko]);
        }
        #pragma unroll
        for (int i = 0; i < 2; ++i) {
            #pragma unroll
            for (int jq = 0; jq < 2; ++jq) {
                acc[i][jq] = mfma16(x1[i], y1[jq], acc[i][jq]);
                acc[i][jq] = mfma16(x2[i], y2[jq], acc[i][jq]);
            }
        }
        __syncthreads();
    }
    #pragma unroll
    for (int i = 0; i < 2; ++i) {
        #pragma unroll
        for (int jq = 0; jq < 2; ++jq) {
            int col = bn + wn + jq * 16 + lr;
            float bv = bias[col];
            #pragma unroll
            for (int q = 0; q < 4; ++q) {
                int row = bm + wm + i * 16 + (lane >> 4) * 4 + q;
                C[(size_t)row * 1024 + col] = acc[i][jq][q] + bv;
            }
        }
    }
}

// loss over all (t,b) rows; grid 8192, m = t*256+b
__global__ __launch_bounds__(256) void loss_all(
    const float* __restrict__ logits, const float* __restrict__ y,
    float* __restrict__ loss_acc)
{
    int m = blockIdx.x, t = threadIdx.x;
    int tt = m >> 8, b = m & 255;
    const float* lrow = logits + (size_t)m * Y_DIM;
    float l[4];
    #pragma unroll
    for (int i = 0; i < 4; ++i) l[i] = lrow[t + i * 256];
    float mx = fmaxf(fmaxf(l[0], l[1]), fmaxf(l[2], l[3]));
    int lane = t & 63, w = t >> 6;
    for (int off = 32; off; off >>= 1) mx = fmaxf(mx, __shfl_down(mx, off));
    __shared__ float sm[4];
    if (!lane) sm[w] = mx;
    __syncthreads();
    mx = fmaxf(fmaxf(sm[0], sm[1]), fmaxf(sm[2], sm[3]));
    float es = 0.f;
    #pragma unroll
    for (int i = 0; i < 4; ++i) es += expf(l[i] - mx);
    for (int off = 32; off; off >>= 1) es += __shfl_down(es, off);
    __shared__ float ss[4];
    if (!lane) ss[w] = es;
    __syncthreads();
    float sum = ss[0] + ss[1] + ss[2] + ss[3];
    float logZ = mx + logf(sum);
    const float* yrow = y + ((size_t)b * T_OUT + tt) * Y_DIM;
    float part = 0.f;
    #pragma unroll
    for (int i = 0; i < 4; ++i) part += yrow[t + i * 256] * (logZ - l[i]);
    for (int off = 32; off; off >>= 1) part += __shfl_down(part, off);
    __shared__ float sp[4];
    if (!lane) sp[w] = part;
    __syncthreads();
    if (t == 0) atomicAdd(loss_acc, sp[0] + sp[1] + sp[2] + sp[3]);
}

__global__ __launch_bounds__(256) void ysum_kernel(
    const float* __restrict__ y, float* __restrict__ ysum, int n)
{
    float s = 0.f;
    for (int i = blockIdx.x * 256 + threadIdx.x; i < n; i += gridDim.x * 256)
        s += y[i];
    int lane = threadIdx.x & 63, w = threadIdx.x >> 6;
    for (int off = 32; off; off >>= 1) s += __shfl_down(s, off);
    __shared__ float sw[4];
    if (!lane) sw[w] = s;
    __syncthreads();
    if (!threadIdx.x) atomicAdd(ysum, sw[0] + sw[1] + sw[2] + sw[3]);
}

__global__ __launch_bounds__(256) void init_kernel(
    float* __restrict__ h0, float* __restrict__ h1,
    short* __restrict__ h0b, short* __restrict__ h1b,
    float* __restrict__ loss, float* __restrict__ ysum)
{
    int i = blockIdx.x * 256 + threadIdx.x;   // 0..B*H-1
    h0[i] = 0.f; h1[i] = 0.f; h0b[i] = 0; h1b[i] = 0;
    if (i == 0) { *loss = 0.f; *ysum = 0.f; }
}

__global__ void final_kernel(const float* __restrict__ loss,
                             const float* __restrict__ ysum,
                             float* __restrict__ out)
{
    if (threadIdx.x == 0) out[0] = loss[0] / ysum[0];
}

// ---------------------------------------------------------------------------
extern "C" void kernel_launch(void* const* d_in, const int* in_sizes, int n_in,
                              void* d_out, int out_size, void* d_ws, size_t ws_size,
                              hipStream_t stream)
{
    const int*   x     = (const int*)d_in[0];
    const float* y     = (const float*)d_in[1];
    const float* emb   = (const float*)d_in[2];
    const float* eWih0 = (const float*)d_in[3];
    const float* eWhh0 = (const float*)d_in[4];
    const float* ebih0 = (const float*)d_in[5];
    const float* ebhh0 = (const float*)d_in[6];
    const float* eWih1 = (const float*)d_in[7];
    const float* eWhh1 = (const float*)d_in[8];
    const float* ebih1 = (const float*)d_in[9];
    const float* ebhh1 = (const float*)d_in[10];
    const float* dWih0 = (const float*)d_in[11];
    const float* dWhh0 = (const float*)d_in[12];
    const float* dbih0 = (const float*)d_in[13];
    const float* dbhh0 = (const float*)d_in[14];
    const float* dWih1 = (const float*)d_in[15];
    const float* dWhh1 = (const float*)d_in[16];
    const float* dbih1 = (const float*)d_in[17];
    const float* dbhh1 = (const float*)d_in[18];
    const float* mapW  = (const float*)d_in[19];
    const float* mapb  = (const float*)d_in[20];
    float* out = (float*)d_out;

    // ---- workspace layout (~200 MB live peak; aliases reuse dead regions) ----
    char* p = (char*)d_ws;
    auto take = [&](size_t n) { char* q = p; p += (n + 255) & ~(size_t)255; return q; };
    short* enc_bf = (short*)take((size_t)T_IN * BATCH * H_DIM * 2);   // 134 MB
    char* wslab = p;
    short* eWih0b = (short*)take((size_t)G_DIM * E_DIM * 2);
    short* eWhh0b = (short*)take((size_t)G_DIM * H_DIM * 2);
    short* eWih1b = (short*)take((size_t)G_DIM * H_DIM * 2);
    short* eWhh1b = (short*)take((size_t)G_DIM * H_DIM * 2);
    short* dWih0b = (short*)take((size_t)G_DIM * Y_DIM * 2);
    short* dWhh0b = (short*)take((size_t)G_DIM * H_DIM * 2);
    short* dWih1b = (short*)take((size_t)G_DIM * H_DIM * 2);
    short* dWhh1b = (short*)take((size_t)G_DIM * H_DIM * 2);
    short* mapWb  = (short*)take((size_t)Y_DIM * 2 * H_DIM * 2);
    float* h0f[2]; float* h1f[2]; short* h0b[2]; short* h1b[2];
    for (int i = 0; i < 2; ++i) {
        h0f[i] = (float*)take((size_t)BATCH * H_DIM * 4);
        h1f[i] = (float*)take((size_t)BATCH * H_DIM * 4);
        h0b[i] = (short*)take((size_t)BATCH * H_DIM * 2);
        h1b[i] = (short*)take((size_t)BATCH * H_DIM * 2);
    }
    short* h2all = (short*)take((size_t)T_OUT * BATCH * H_DIM * 2);   // 16.8 MB
    float* loss_acc = (float*)take(256);
    float* ysum = loss_acc + 1;
    // aliases onto dead regions:
    float* logits  = (float*)enc_bf;                       // enc dead at map time
    short* attn_bf = (short*)wslab;                        // over dead enc weights
    float* S       = (float*)(wslab + (size_t)20 * 1024 * 1024);

    dim3 blk(256);

    // ---- weight conversion ----
    f32_to_bf16<<<dim3(512), blk, 0, stream>>>(eWih0, eWih0b, G_DIM * E_DIM / 4);
    f32_to_bf16<<<dim3(512), blk, 0, stream>>>(eWhh0, eWhh0b, G_DIM * H_DIM / 4);
    f32_to_bf16<<<dim3(512), blk, 0, stream>>>(eWih1, eWih1b, G_DIM * H_DIM / 4);
    f32_to_bf16<<<dim3(512), blk, 0, stream>>>(eWhh1, eWhh1b, G_DIM * H_DIM / 4);
    f32_to_bf16<<<dim3(512), blk, 0, stream>>>(dWih0, dWih0b, G_DIM * Y_DIM / 4);
    f32_to_bf16<<<dim3(512), blk, 0, stream>>>(dWhh0, dWhh0b, G_DIM * H_DIM / 4);
    f32_to_bf16<<<dim3(512), blk, 0, stream>>>(dWih1, dWih1b, G_DIM * H_DIM / 4);
    f32_to_bf16<<<dim3(512), blk, 0, stream>>>(dWhh1, dWhh1b, G_DIM * H_DIM / 4);
    f32_to_bf16<<<dim3(512), blk, 0, stream>>>(mapW, mapWb, Y_DIM * 2 * H_DIM / 4);

    init_kernel<<<dim3(BATCH * H_DIM / 256), blk, 0, stream>>>(
        h0f[0], h1f[0], h0b[0], h1b[0], loss_acc, ysum);
    ysum_kernel<<<dim3(2048), blk, 0, stream>>>(y, ysum, BATCH * T_OUT * Y_DIM);

    // -------- encoder: diagonal pipeline, launch k = layer0(k) || layer1(k-1) ----
    for (int k = 0; k <= T_IN; ++k) {
        CellArgs A = {}, B = {};
        A.active = (k < T_IN);
        if (A.active) {
            A.Af = emb; A.gat = x + k; A.gs = T_IN; A.lda = E_DIM; A.Kx = E_DIM;
            A.Wih = eWih0b; A.Whh = eWhh0b; A.bih = ebih0; A.bhh = ebhh0;
            A.hbf = h0b[k & 1]; A.hf = h0f[k & 1];
            A.houtf = h0f[(k + 1) & 1]; A.houtbf = h0b[(k + 1) & 1];
        }
        B.active = (k >= 1);
        if (B.active) {
            B.Ab = h0b[k & 1]; B.lda = H_DIM; B.Kx = H_DIM;
            B.Wih = eWih1b; B.Whh = eWhh1b; B.bih = ebih1; B.bhh = ebhh1;
            B.hbf = h1b[(k - 1) & 1]; B.hf = h1f[(k - 1) & 1];
            B.houtf = h1f[k & 1]; B.houtbf = h1b[k & 1];
            B.copy = enc_bf + (size_t)(k - 1) * BATCH * H_DIM;
        }
        cell3<<<dim3(512), blk, 0, stream>>>(A, B);
    }

    // -------- decoder GRU chain (teacher-forced): same pipeline ----
    for (int k = 0; k <= T_OUT; ++k) {
        CellArgs A = {}, B = {};
        A.active = (k < T_OUT);
        if (A.active) {
            if (k == 0) {
                A.Kx = 0;   // y_in = 0: gi = bias only
            } else {
                A.Af = y + (size_t)(k - 1) * Y_DIM;
                A.lda = T_OUT * Y_DIM; A.Kx = Y_DIM;
            }
            A.Wih = dWih0b; A.Whh = dWhh0b; A.bih = dbih0; A.bhh = dbhh0;
            A.hbf = h0b[k & 1]; A.hf = h0f[k & 1];
            A.houtf = h0f[(k + 1) & 1]; A.houtbf = h0b[(k + 1) & 1];
        }
        B.active = (k >= 1);
        if (B.active) {
            B.Ab = h0b[k & 1]; B.lda = H_DIM; B.Kx = H_DIM;
            B.Wih = dWih1b; B.Whh = dWhh1b; B.bih = dbih1; B.bhh = dbhh1;
            B.hbf = h1b[(k - 1) & 1]; B.hf = h1f[(k - 1) & 1];
            B.houtf = h1f[k & 1]; B.houtbf = h1b[k & 1];
            B.copy = h2all + (size_t)(k - 1) * BATCH * H_DIM;
        }
        cell3<<<dim3(512), blk, 0, stream>>>(A, B);
    }

    // -------- batched attention + map + loss over all 32 decoder steps ----
    score_gemm<<<dim3(4, 256), blk, 0, stream>>>(h2all, enc_bf, S);
    softmax_all<<<dim3(8192), blk, 0, stream>>>(S);
    attn_apply_all<<<dim3(4, 256), blk, 0, stream>>>(enc_bf, S, attn_bf);
    map_gemm<<<dim3(128, 16), blk, 0, stream>>>(attn_bf, h2all, mapWb, mapb, logits);
    loss_all<<<dim3(8192), blk, 0, stream>>>(logits, y, loss_acc);

    final_kernel<<<dim3(1), dim3(64), 0, stream>>>(loss_acc, ysum, out);
}

// Round 8
// 17044.472 us; speedup vs baseline: 1.9000x; 1.3167x over previous
//
#include <hip/hip_runtime.h>
#include <hip/hip_bf16.h>
#include <math.h>

#define BATCH 256
#define T_IN 256
#define T_OUT 32
#define E_DIM 512
#define H_DIM 1024
#define Y_DIM 1024
#define G_DIM 3072  // 3*H
#define RS 34       // LDS row stride in shorts

typedef __attribute__((ext_vector_type(8))) __bf16 bf16x8;
typedef __attribute__((ext_vector_type(4))) float f32x4;
typedef __attribute__((ext_vector_type(4))) unsigned int u32x4;

__device__ __forceinline__ unsigned short f2bf_raw(float x) {
    unsigned int u = __builtin_bit_cast(unsigned int, x);
    u += 0x7FFFu + ((u >> 16) & 1u);
    return (unsigned short)(u >> 16);
}
__device__ __forceinline__ float bf2f(short s) {
    unsigned int u = ((unsigned int)(unsigned short)s) << 16;
    return __builtin_bit_cast(float, u);
}
__device__ __forceinline__ f32x4 mfma16(bf16x8 a, bf16x8 b, f32x4 c) {
    return __builtin_amdgcn_mfma_f32_16x16x32_bf16(a, b, c, 0, 0, 0);
}
__device__ __forceinline__ bf16x8 ldsb8(const short* p) {
    return __builtin_bit_cast(bf16x8, *(const u32x4*)p);
}
__device__ __forceinline__ bf16x8 asbf8(u32x4 v) {
    return __builtin_bit_cast(bf16x8, v);
}
__device__ __forceinline__ u32x4 conv_f32x8(const float* p) {
    float4 f0 = *(const float4*)p;
    float4 f1 = *(const float4*)(p + 4);
    u32x4 v;
    v.x = ((unsigned)f2bf_raw(f0.y) << 16) | f2bf_raw(f0.x);
    v.y = ((unsigned)f2bf_raw(f0.w) << 16) | f2bf_raw(f0.z);
    v.z = ((unsigned)f2bf_raw(f1.y) << 16) | f2bf_raw(f1.x);
    v.w = ((unsigned)f2bf_raw(f1.w) << 16) | f2bf_raw(f1.z);
    return v;
}

// ---------------------------------------------------------------------------
// f32 -> bf16 convert (weights, once per call)
// ---------------------------------------------------------------------------
__global__ __launch_bounds__(256) void f32_to_bf16(
    const float* __restrict__ src, short* __restrict__ dst, int n4)
{
    for (int i = blockIdx.x * 256 + threadIdx.x; i < n4; i += gridDim.x * 256) {
        float4 f = *(const float4*)(src + 4 * (size_t)i);
        short4 o;
        o.x = (short)f2bf_raw(f.x);
        o.y = (short)f2bf_raw(f.y);
        o.z = (short)f2bf_raw(f.z);
        o.w = (short)f2bf_raw(f.w);
        *(short4*)(dst + 4 * (size_t)i) = o;
    }
}

// ---------------------------------------------------------------------------
// Fused GRU cell v4: W operand streamed global->registers (L2-resident via
// XCD swizzle), prefetched one K-step ahead — removes W from LDS entirely
// (the R4-R7 bodies were LDS-throughput + barrier bound, 14:1 LDS:MFMA).
// A operands (x,h) in double-buffered LDS, ONE barrier per K-step.
// Block = 32 rows x 64 h-cols; 4 waves, each 32r x 16hc (2 m-frags).
// Per wave per K-step: 6 W VMEM(16B) + 4 A ds_read + 12 MFMA.
// Two cells per launch (blockIdx >= 128 -> B); 256 blocks = 1/CU.
// ---------------------------------------------------------------------------
struct CellArgs {
    const float* Af; const short* Ab; const int* gat; int gs; int lda; int Kx;
    const short* Wih; const short* Whh;
    const float* bih; const float* bhh;
    const short* hbf;   // bf16 h_prev (GEMM operand)
    const float* hf;    // f32  h_prev (GRU combine)
    float* houtf; short* houtbf; short* copy;
    int active;
};

__global__ __launch_bounds__(256) void cell4(CellArgs cA, CellArgs cB)
{
    const int id = blockIdx.x;
    const CellArgs a = (id >= 128) ? cB : cA;
    if (!a.active) return;
    const int cid = id & 127;
    // XCD swizzle: XCD = id%8 = cid%8; per-XCD W slice (both cells) ~2.75MB < 4MB L2
    const int nt = (cid & 7) * 2 + ((cid >> 3) & 1);   // 0..15 (64 h-cols)
    const int mt = cid >> 4;                           // 0..7  (32 rows)
    const int bm = mt * 32, bn = nt * 64;

    __shared__ __align__(16) short As[2 * 2 * 32 * RS];  // [buf][src][32r][RS]

    const int tid = threadIdx.x;
    const int lane = tid & 63;
    const int w = tid >> 6;          // wave -> 16-hcol quarter
    const int lr = lane & 15, lk = lane >> 4;
    const int Kx = a.Kx;

    // ---- A staging: 1 x 16B chunk per thread per K-step ----
    const int ss = tid >> 7;          // 0 = x-src, 1 = h-src
    const int sr = (tid >> 2) & 31;   // tile row
    const int ch = (tid & 3) * 8;     // chunk offset (shorts)
    const float* axf = nullptr; const short* axb = nullptr;
    if (ss == 0 && Kx > 0) {
        if (a.Ab) {
            axb = a.Ab + (size_t)(bm + sr) * a.lda + ch;
        } else {
            int ridx = a.gat ? a.gat[(size_t)(bm + sr) * a.gs] : (bm + sr);
            axf = a.Af + (size_t)ridx * a.lda + ch;
        }
    }
    const short* ahs = a.hbf + (size_t)(bm + sr) * H_DIM + ch;
    const int adoff = ss * (32 * RS) + sr * RS + ch;

    // ---- W per-lane global pointers (B-fragment: lane = col lr, k-chunk lk) ----
    const int col = bn + w * 16 + lr;
    const short* wihp[3]; const short* whhp[3];
    #pragma unroll
    for (int g = 0; g < 3; ++g) {
        wihp[g] = a.Wih + (size_t)(g * H_DIM + col) * Kx + lk * 8;
        whhp[g] = a.Whh + (size_t)(g * H_DIM + col) * H_DIM + lk * 8;
    }

    // A-frag LDS read offsets (per wave: 2 srcs x 2 m-frags)
    const int ax0o = 0 * (32 * RS) + lr * RS + lk * 8;
    const int ax1o = 0 * (32 * RS) + (16 + lr) * RS + lk * 8;
    const int ah0o = 1 * (32 * RS) + lr * RS + lk * 8;
    const int ah1o = 1 * (32 * RS) + (16 + lr) * RS + lk * 8;

    f32x4 zf = {0.f, 0.f, 0.f, 0.f};
    f32x4 accI[3][2] = {{zf, zf}, {zf, zf}, {zf, zf}};
    f32x4 accH[3][2] = {{zf, zf}, {zf, zf}, {zf, zf}};

    // ---- prologue: stage A(0) into buf0; preload W(0) ----
    {
        u32x4 av = {0u, 0u, 0u, 0u};
        bool doA = (ss == 1) || (Kx > 0);
        if (ss == 1)      av = *(const u32x4*)(ahs);
        else if (axb)     av = *(const u32x4*)(axb);
        else if (axf)     av = conv_f32x8(axf);
        if (doA) *(u32x4*)&As[adoff] = av;
    }
    u32x4 wI[3], wH[3];
    #pragma unroll
    for (int g = 0; g < 3; ++g) {
        wH[g] = *(const u32x4*)(whhp[g]);
        if (Kx > 0) wI[g] = *(const u32x4*)(wihp[g]);
    }
    __syncthreads();

    int buf = 0;
    for (int k0 = 0; k0 < H_DIM; k0 += 32) {
        const int kn = k0 + 32;
        const bool more = kn < H_DIM;

        // ---- stage A(kn) into buf^1 (ds_write; completes before next barrier) ----
        if (more) {
            u32x4 av = {0u, 0u, 0u, 0u};
            bool doA = (ss == 1) || (kn < Kx);
            if (ss == 1)              av = *(const u32x4*)(ahs + kn);
            else if (kn < Kx) {
                if (axb) av = *(const u32x4*)(axb + kn);
                else     av = conv_f32x8(axf + kn);
            }
            if (doA) *(u32x4*)&As[(buf ^ 1) * (2 * 32 * RS) + adoff] = av;
        }
        // ---- prefetch W(kn) into regs (lands under this step's MFMA) ----
        u32x4 wIn[3], wHn[3];
        if (more) {
            #pragma unroll
            for (int g = 0; g < 3; ++g) {
                wHn[g] = *(const u32x4*)(whhp[g] + kn);
                if (kn < Kx) wIn[g] = *(const u32x4*)(wihp[g] + kn);
            }
        }

        // ---- compute k0 ----
        const short* ab = &As[buf * (2 * 32 * RS)];
        bf16x8 aH0 = ldsb8(ab + ah0o), aH1 = ldsb8(ab + ah1o);
        #pragma unroll
        for (int g = 0; g < 3; ++g) {
            bf16x8 wh = asbf8(wH[g]);
            accH[g][0] = mfma16(aH0, wh, accH[g][0]);
            accH[g][1] = mfma16(aH1, wh, accH[g][1]);
        }
        if (k0 < Kx) {
            bf16x8 aX0 = ldsb8(ab + ax0o), aX1 = ldsb8(ab + ax1o);
            #pragma unroll
            for (int g = 0; g < 3; ++g) {
                bf16x8 wi = asbf8(wI[g]);
                accI[g][0] = mfma16(aX0, wi, accI[g][0]);
                accI[g][1] = mfma16(aX1, wi, accI[g][1]);
            }
        }
        __syncthreads();   // buf^1 staged for next iter; buf reads done before overwrite

        #pragma unroll
        for (int g = 0; g < 3; ++g) { wH[g] = wHn[g]; wI[g] = wIn[g]; }
        buf ^= 1;
    }

    // ---- GRU epilogue (torch gate order r,z,n) ----
    const float bi0 = a.bih[col], bi1 = a.bih[H_DIM + col], bi2 = a.bih[2 * H_DIM + col];
    const float bh0 = a.bhh[col], bh1 = a.bhh[H_DIM + col], bh2 = a.bhh[2 * H_DIM + col];
    #pragma unroll
    for (int mf = 0; mf < 2; ++mf) {
        #pragma unroll
        for (int q = 0; q < 4; ++q) {
            int row = bm + mf * 16 + lk * 4 + q;
            float ir = accI[0][mf][q] + bi0, hr = accH[0][mf][q] + bh0;
            float iz = accI[1][mf][q] + bi1, hz = accH[1][mf][q] + bh1;
            float in_ = accI[2][mf][q] + bi2, hn = accH[2][mf][q] + bh2;
            float r = 1.f / (1.f + expf(-(ir + hr)));
            float z = 1.f / (1.f + expf(-(iz + hz)));
            float n = tanhf(in_ + r * hn);
            size_t oi = (size_t)row * H_DIM + col;
            float hv = a.hf[oi];
            float o = (1.f - z) * n + z * hv;
            a.houtf[oi] = o;
            short ob = (short)f2bf_raw(o);
            a.houtbf[oi] = ob;
            if (a.copy) a.copy[oi] = ob;
        }
    }
}

// ---------------------------------------------------------------------------
// scores: S[b][t][s] = dot(h2all[t][b][:], enc[s][b][:]) — MFMA, all t at once
// ---------------------------------------------------------------------------
__global__ __launch_bounds__(256) void score_gemm(
    const short* __restrict__ h2all, const short* __restrict__ enc,
    float* __restrict__ S)
{
    const int st = blockIdx.x;
    const int b = blockIdx.y;
    __shared__ __align__(16) short Hs[32 * 40];
    __shared__ __align__(16) short Es[64 * 40];
    const int tid = threadIdx.x;
    const int ch = (tid & 3) * 8;
    const int hrow = (tid >> 2) & 31;
    const int erow = tid >> 2;
    const short* hsrc = h2all + ((size_t)hrow * BATCH + b) * H_DIM + ch;
    const short* esrc = enc + ((size_t)(st * 64 + erow) * BATCH + b) * H_DIM + ch;
    short* hdst = &Hs[hrow * 40 + ch];
    short* edst = &Es[erow * 40 + ch];

    const int lane = tid & 63, w = tid >> 6;
    const int lr = lane & 15, ko = (lane >> 4) * 8;
    f32x4 acc0 = {0.f, 0.f, 0.f, 0.f}, acc1 = acc0;
    for (int k0 = 0; k0 < H_DIM; k0 += 32) {
        if (tid < 128) *(u32x4*)hdst = *(const u32x4*)(hsrc + k0);
        *(u32x4*)edst = *(const u32x4*)(esrc + k0);
        __syncthreads();
        bf16x8 e = ldsb8(&Es[(w * 16 + lr) * 40 + ko]);
        bf16x8 h0v = ldsb8(&Hs[lr * 40 + ko]);
        bf16x8 h1v = ldsb8(&Hs[(16 + lr) * 40 + ko]);
        acc0 = mfma16(h0v, e, acc0);
        acc1 = mfma16(h1v, e, acc1);
        __syncthreads();
    }
    int s = st * 64 + w * 16 + lr;
    #pragma unroll
    for (int q = 0; q < 4; ++q) {
        int t0 = (lane >> 4) * 4 + q;
        S[(size_t)b * 8192 + (size_t)t0 * 256 + s] = acc0[q];
        S[(size_t)b * 8192 + (size_t)(t0 + 16) * 256 + s] = acc1[q];
    }
}

// softmax over s (256) per (b,t) row; grid 8192
__global__ __launch_bounds__(256) void softmax_all(float* __restrict__ S)
{
    size_t base = (size_t)blockIdx.x * 256;
    int t = threadIdx.x;
    float v = S[base + t];
    int lane = t & 63, w = t >> 6;
    float m = v;
    for (int off = 32; off; off >>= 1) m = fmaxf(m, __shfl_down(m, off));
    __shared__ float r1[4];
    if (!lane) r1[w] = m;
    __syncthreads();
    m = fmaxf(fmaxf(r1[0], r1[1]), fmaxf(r1[2], r1[3]));
    float ex = expf(v - m);
    float s = ex;
    for (int off = 32; off; off >>= 1) s += __shfl_down(s, off);
    __shared__ float r2[4];
    if (!lane) r2[w] = s;
    __syncthreads();
    s = r2[0] + r2[1] + r2[2] + r2[3];
    S[base + t] = ex / s;
}

// attn_bf[m=t*256+b][h] = sum_s alpha[b][t][s] * enc[s][b][h]; grid (4 tc, 256 b)
__global__ __launch_bounds__(256) void attn_apply_all(
    const short* __restrict__ enc, const float* __restrict__ S,
    short* __restrict__ attn_bf)
{
    const int tc = blockIdx.x, b = blockIdx.y;
    __shared__ float al[8][256];
    const int tid = threadIdx.x;
    #pragma unroll
    for (int ti = 0; ti < 8; ++ti)
        al[ti][tid] = S[(size_t)b * 8192 + (size_t)(tc * 8 + ti) * 256 + tid];
    __syncthreads();
    float acc[8][4] = {};
    const short* eb = enc + (size_t)b * H_DIM + tid;
    for (int s = 0; s < 256; ++s) {
        const short* er = eb + (size_t)s * (BATCH * H_DIM);
        float e0 = bf2f(er[0]), e1 = bf2f(er[256]);
        float e2 = bf2f(er[512]), e3 = bf2f(er[768]);
        #pragma unroll
        for (int ti = 0; ti < 8; ++ti) {
            float av = al[ti][s];
            acc[ti][0] += av * e0; acc[ti][1] += av * e1;
            acc[ti][2] += av * e2; acc[ti][3] += av * e3;
        }
    }
    #pragma unroll
    for (int ti = 0; ti < 8; ++ti) {
        size_t m = (size_t)(tc * 8 + ti) * 256 + b;
        #pragma unroll
        for (int i = 0; i < 4; ++i)
            attn_bf[m * H_DIM + tid + i * 256] = (short)f2bf_raw(acc[ti][i]);
    }
}

// ---------------------------------------------------------------------------
// logits[m][n] = attn[m]@mapW[n][:1024] + h2[m]@mapW[n][1024:] + b[n]
// ---------------------------------------------------------------------------
__global__ __launch_bounds__(256) void map_gemm(
    const short* __restrict__ A1, const short* __restrict__ A2,
    const short* __restrict__ Wm, const float* __restrict__ bias,
    float* __restrict__ C)
{
    const int bm = blockIdx.x * 64, bn = blockIdx.y * 64;
    __shared__ __align__(16) short S1[64 * 40], S2[64 * 40], T1[64 * 40], T2[64 * 40];
    const int tid = threadIdx.x;
    const int r = tid >> 2, ch = (tid & 3) * 8;
    const short* a1 = A1 + (size_t)(bm + r) * 1024 + ch;
    const short* a2 = A2 + (size_t)(bm + r) * 1024 + ch;
    const short* w1 = Wm + (size_t)(bn + r) * 2048 + ch;
    const short* w2 = w1 + 1024;
    const int lane = tid & 63, w = tid >> 6;
    const int wm = (w >> 1) * 32, wn = (w & 1) * 32;
    const int lr = lane & 15, ko = (lane >> 4) * 8;
    f32x4 acc[2][2] = {{{0.f,0.f,0.f,0.f}}};
    for (int k0 = 0; k0 < 1024; k0 += 32) {
        *(u32x4*)&S1[r * 40 + ch] = *(const u32x4*)(a1 + k0);
        *(u32x4*)&S2[r * 40 + ch] = *(const u32x4*)(a2 + k0);
        *(u32x4*)&T1[r * 40 + ch] = *(const u32x4*)(w1 + k0);
        *(u32x4*)&T2[r * 40 + ch] = *(const u32x4*)(w2 + k0);
        __syncthreads();
        bf16x8 x1[2], x2[2], y1[2], y2[2];
        #pragma unroll
        for (int i = 0; i < 2; ++i) {
            x1[i] = ldsb8(&S1[(wm + i * 16 + lr) * 40 + ko]);
            x2[i] = ldsb8(&S2[(wm + i * 16 + lr) * 40 + ko]);
            y1[i] = ldsb8(&T1[(wn + i * 16 + lr) * 40 + ko]);
            y2[i] = ldsb8(&T2[(wn + i * 16 + lr) * 40 + ko]);
        }
        #pragma unroll
        for (int i = 0; i < 2; ++i) {
            #pragma unroll
            for (int jq = 0; jq < 2; ++jq) {
                acc[i][jq] = mfma16(x1[i], y1[jq], acc[i][jq]);
                acc[i][jq] = mfma16(x2[i], y2[jq], acc[i][jq]);
            }
        }
        __syncthreads();
    }
    #pragma unroll
    for (int i = 0; i < 2; ++i) {
        #pragma unroll
        for (int jq = 0; jq < 2; ++jq) {
            int col = bn + wn + jq * 16 + lr;
            float bv = bias[col];
            #pragma unroll
            for (int q = 0; q < 4; ++q) {
                int row = bm + wm + i * 16 + (lane >> 4) * 4 + q;
                C[(size_t)row * 1024 + col] = acc[i][jq][q] + bv;
            }
        }
    }
}

// loss over all (t,b) rows; grid 8192, m = t*256+b
__global__ __launch_bounds__(256) void loss_all(
    const float* __restrict__ logits, const float* __restrict__ y,
    float* __restrict__ loss_acc)
{
    int m = blockIdx.x, t = threadIdx.x;
    int tt = m >> 8, b = m & 255;
    const float* lrow = logits + (size_t)m * Y_DIM;
    float l[4];
    #pragma unroll
    for (int i = 0; i < 4; ++i) l[i] = lrow[t + i * 256];
    float mx = fmaxf(fmaxf(l[0], l[1]), fmaxf(l[2], l[3]));
    int lane = t & 63, w = t >> 6;
    for (int off = 32; off; off >>= 1) mx = fmaxf(mx, __shfl_down(mx, off));
    __shared__ float sm[4];
    if (!lane) sm[w] = mx;
    __syncthreads();
    mx = fmaxf(fmaxf(sm[0], sm[1]), fmaxf(sm[2], sm[3]));
    float es = 0.f;
    #pragma unroll
    for (int i = 0; i < 4; ++i) es += expf(l[i] - mx);
    for (int off = 32; off; off >>= 1) es += __shfl_down(es, off);
    __shared__ float ss[4];
    if (!lane) ss[w] = es;
    __syncthreads();
    float sum = ss[0] + ss[1] + ss[2] + ss[3];
    float logZ = mx + logf(sum);
    const float* yrow = y + ((size_t)b * T_OUT + tt) * Y_DIM;
    float part = 0.f;
    #pragma unroll
    for (int i = 0; i < 4; ++i) part += yrow[t + i * 256] * (logZ - l[i]);
    for (int off = 32; off; off >>= 1) part += __shfl_down(part, off);
    __shared__ float sp[4];
    if (!lane) sp[w] = part;
    __syncthreads();
    if (t == 0) atomicAdd(loss_acc, sp[0] + sp[1] + sp[2] + sp[3]);
}

__global__ __launch_bounds__(256) void ysum_kernel(
    const float* __restrict__ y, float* __restrict__ ysum, int n)
{
    float s = 0.f;
    for (int i = blockIdx.x * 256 + threadIdx.x; i < n; i += gridDim.x * 256)
        s += y[i];
    int lane = threadIdx.x & 63, w = threadIdx.x >> 6;
    for (int off = 32; off; off >>= 1) s += __shfl_down(s, off);
    __shared__ float sw[4];
    if (!lane) sw[w] = s;
    __syncthreads();
    if (!threadIdx.x) atomicAdd(ysum, sw[0] + sw[1] + sw[2] + sw[3]);
}

__global__ __launch_bounds__(256) void init_kernel(
    float* __restrict__ h0, float* __restrict__ h1,
    short* __restrict__ h0b, short* __restrict__ h1b,
    float* __restrict__ loss, float* __restrict__ ysum)
{
    int i = blockIdx.x * 256 + threadIdx.x;   // 0..B*H-1
    h0[i] = 0.f; h1[i] = 0.f; h0b[i] = 0; h1b[i] = 0;
    if (i == 0) { *loss = 0.f; *ysum = 0.f; }
}

__global__ void final_kernel(const float* __restrict__ loss,
                             const float* __restrict__ ysum,
                             float* __restrict__ out)
{
    if (threadIdx.x == 0) out[0] = loss[0] / ysum[0];
}

// ---------------------------------------------------------------------------
extern "C" void kernel_launch(void* const* d_in, const int* in_sizes, int n_in,
                              void* d_out, int out_size, void* d_ws, size_t ws_size,
                              hipStream_t stream)
{
    const int*   x     = (const int*)d_in[0];
    const float* y     = (const float*)d_in[1];
    const float* emb   = (const float*)d_in[2];
    const float* eWih0 = (const float*)d_in[3];
    const float* eWhh0 = (const float*)d_in[4];
    const float* ebih0 = (const float*)d_in[5];
    const float* ebhh0 = (const float*)d_in[6];
    const float* eWih1 = (const float*)d_in[7];
    const float* eWhh1 = (const float*)d_in[8];
    const float* ebih1 = (const float*)d_in[9];
    const float* ebhh1 = (const float*)d_in[10];
    const float* dWih0 = (const float*)d_in[11];
    const float* dWhh0 = (const float*)d_in[12];
    const float* dbih0 = (const float*)d_in[13];
    const float* dbhh0 = (const float*)d_in[14];
    const float* dWih1 = (const float*)d_in[15];
    const float* dWhh1 = (const float*)d_in[16];
    const float* dbih1 = (const float*)d_in[17];
    const float* dbhh1 = (const float*)d_in[18];
    const float* mapW  = (const float*)d_in[19];
    const float* mapb  = (const float*)d_in[20];
    float* out = (float*)d_out;

    // ---- workspace layout (~200 MB live peak; aliases reuse dead regions) ----
    char* p = (char*)d_ws;
    auto take = [&](size_t n) { char* q = p; p += (n + 255) & ~(size_t)255; return q; };
    short* enc_bf = (short*)take((size_t)T_IN * BATCH * H_DIM * 2);   // 134 MB
    char* wslab = p;
    short* eWih0b = (short*)take((size_t)G_DIM * E_DIM * 2);
    short* eWhh0b = (short*)take((size_t)G_DIM * H_DIM * 2);
    short* eWih1b = (short*)take((size_t)G_DIM * H_DIM * 2);
    short* eWhh1b = (short*)take((size_t)G_DIM * H_DIM * 2);
    short* dWih0b = (short*)take((size_t)G_DIM * Y_DIM * 2);
    short* dWhh0b = (short*)take((size_t)G_DIM * H_DIM * 2);
    short* dWih1b = (short*)take((size_t)G_DIM * H_DIM * 2);
    short* dWhh1b = (short*)take((size_t)G_DIM * H_DIM * 2);
    short* mapWb  = (short*)take((size_t)Y_DIM * 2 * H_DIM * 2);
    float* h0f[2]; float* h1f[2]; short* h0b[2]; short* h1b[2];
    for (int i = 0; i < 2; ++i) {
        h0f[i] = (float*)take((size_t)BATCH * H_DIM * 4);
        h1f[i] = (float*)take((size_t)BATCH * H_DIM * 4);
        h0b[i] = (short*)take((size_t)BATCH * H_DIM * 2);
        h1b[i] = (short*)take((size_t)BATCH * H_DIM * 2);
    }
    short* h2all = (short*)take((size_t)T_OUT * BATCH * H_DIM * 2);   // 16.8 MB
    float* loss_acc = (float*)take(256);
    float* ysum = loss_acc + 1;
    // aliases onto dead regions:
    float* logits  = (float*)enc_bf;                       // enc dead at map time
    short* attn_bf = (short*)wslab;                        // over dead enc weights
    float* S       = (float*)(wslab + (size_t)20 * 1024 * 1024);

    dim3 blk(256);

    // ---- weight conversion ----
    f32_to_bf16<<<dim3(512), blk, 0, stream>>>(eWih0, eWih0b, G_DIM * E_DIM / 4);
    f32_to_bf16<<<dim3(512), blk, 0, stream>>>(eWhh0, eWhh0b, G_DIM * H_DIM / 4);
    f32_to_bf16<<<dim3(512), blk, 0, stream>>>(eWih1, eWih1b, G_DIM * H_DIM / 4);
    f32_to_bf16<<<dim3(512), blk, 0, stream>>>(eWhh1, eWhh1b, G_DIM * H_DIM / 4);
    f32_to_bf16<<<dim3(512), blk, 0, stream>>>(dWih0, dWih0b, G_DIM * Y_DIM / 4);
    f32_to_bf16<<<dim3(512), blk, 0, stream>>>(dWhh0, dWhh0b, G_DIM * H_DIM / 4);
    f32_to_bf16<<<dim3(512), blk, 0, stream>>>(dWih1, dWih1b, G_DIM * H_DIM / 4);
    f32_to_bf16<<<dim3(512), blk, 0, stream>>>(dWhh1, dWhh1b, G_DIM * H_DIM / 4);
    f32_to_bf16<<<dim3(512), blk, 0, stream>>>(mapW, mapWb, Y_DIM * 2 * H_DIM / 4);

    init_kernel<<<dim3(BATCH * H_DIM / 256), blk, 0, stream>>>(
        h0f[0], h1f[0], h0b[0], h1b[0], loss_acc, ysum);
    ysum_kernel<<<dim3(2048), blk, 0, stream>>>(y, ysum, BATCH * T_OUT * Y_DIM);

    // -------- encoder: diagonal pipeline, launch k = layer0(k) || layer1(k-1) ----
    for (int k = 0; k <= T_IN; ++k) {
        CellArgs A = {}, B = {};
        A.active = (k < T_IN);
        if (A.active) {
            A.Af = emb; A.gat = x + k; A.gs = T_IN; A.lda = E_DIM; A.Kx = E_DIM;
            A.Wih = eWih0b; A.Whh = eWhh0b; A.bih = ebih0; A.bhh = ebhh0;
            A.hbf = h0b[k & 1]; A.hf = h0f[k & 1];
            A.houtf = h0f[(k + 1) & 1]; A.houtbf = h0b[(k + 1) & 1];
        }
        B.active = (k >= 1);
        if (B.active) {
            B.Ab = h0b[k & 1]; B.lda = H_DIM; B.Kx = H_DIM;
            B.Wih = eWih1b; B.Whh = eWhh1b; B.bih = ebih1; B.bhh = ebhh1;
            B.hbf = h1b[(k - 1) & 1]; B.hf = h1f[(k - 1) & 1];
            B.houtf = h1f[k & 1]; B.houtbf = h1b[k & 1];
            B.copy = enc_bf + (size_t)(k - 1) * BATCH * H_DIM;
        }
        cell4<<<dim3(256), blk, 0, stream>>>(A, B);
    }

    // -------- decoder GRU chain (teacher-forced): same pipeline ----
    for (int k = 0; k <= T_OUT; ++k) {
        CellArgs A = {}, B = {};
        A.active = (k < T_OUT);
        if (A.active) {
            if (k == 0) {
                A.Kx = 0;   // y_in = 0: gi = bias only
            } else {
                A.Af = y + (size_t)(k - 1) * Y_DIM;
                A.lda = T_OUT * Y_DIM; A.Kx = Y_DIM;
            }
            A.Wih = dWih0b; A.Whh = dWhh0b; A.bih = dbih0; A.bhh = dbhh0;
            A.hbf = h0b[k & 1]; A.hf = h0f[k & 1];
            A.houtf = h0f[(k + 1) & 1]; A.houtbf = h0b[(k + 1) & 1];
        }
        B.active = (k >= 1);
        if (B.active) {
            B.Ab = h0b[k & 1]; B.lda = H_DIM; B.Kx = H_DIM;
            B.Wih = dWih1b; B.Whh = dWhh1b; B.bih = dbih1; B.bhh = dbhh1;
            B.hbf = h1b[(k - 1) & 1]; B.hf = h1f[(k - 1) & 1];
            B.houtf = h1f[k & 1]; B.houtbf = h1b[k & 1];
            B.copy = h2all + (size_t)(k - 1) * BATCH * H_DIM;
        }
        cell4<<<dim3(256), blk, 0, stream>>>(A, B);
    }

    // -------- batched attention + map + loss over all 32 decoder steps ----
    score_gemm<<<dim3(4, 256), blk, 0, stream>>>(h2all, enc_bf, S);
    softmax_all<<<dim3(8192), blk, 0, stream>>>(S);
    attn_apply_all<<<dim3(4, 256), blk, 0, stream>>>(enc_bf, S, attn_bf);
    map_gemm<<<dim3(128, 16), blk, 0, stream>>>(attn_bf, h2all, mapWb, mapb, logits);
    loss_all<<<dim3(8192), blk, 0, stream>>>(logits, y, loss_acc);

    final_kernel<<<dim3(1), dim3(64), 0, stream>>>(loss_acc, ysum, out);
}